// Round 1
// baseline (74.870 us; speedup 1.0000x reference)
//
#include <hip/hip_runtime.h>

// NeRFDecoderHead: ray-marched occupancy render. ALL I/O is float32.
//   inputs: rays_o (R,3), rays_d (R,3), voxel (1,200,200,16), rgb_recon (3,200,200,16)
//   output: depth (R) ++ rgb_marched (R,3), flat float32.
//
// v2: AoS repack. The march loop is gather-request bound (random ray dirs =>
// 64 divergent lane addresses per load; grids are L1/L2-resident so request
// throughput, not bytes, is the cost). Pre-pack {dens,r,g,b} per voxel into a
// float4 grid in the workspace: 8 corner gathers of dwordx4 per sample instead
// of 32 scalar gathers (~4x fewer serialized line-requests).
//
// Algorithmic notes (unchanged from v1):
//  * probs = diff(min(cumsum(p_raw),1)); saturating scan => early break at c>=1.
//  * Origins strictly inside convex bbox => inside-set is a prefix; at first
//    outside sample only the forced last sample remains: depth += (1-c)*z_last.
//  * Trilinear weights computed once per sample, shared by all 4 channels;
//    accumulation order matches reference (000..111).

namespace {
constexpr int DX = 200, DY = 200, DZ = 16;
constexpr int GRID_N = DX * DY * DZ;   // 640000 per channel
constexpr int NS = 287;                // N_SAMPLES
constexpr float ZSTEP = 0.2f;          // stepsize(0.5) * voxel_size(0.4)
} // namespace

extern "C" __global__ void __launch_bounds__(256)
nerf_pack_kernel(const float* __restrict__ vox,
                 const float* __restrict__ rgbg,
                 float4* __restrict__ pack)
{
    const int i = blockIdx.x * 256 + threadIdx.x;
    if (i >= GRID_N) return;
    float4 v;
    v.x = vox[i];                    // density
    v.y = rgbg[i];                   // r
    v.z = rgbg[GRID_N + i];          // g
    v.w = rgbg[2 * GRID_N + i];      // b
    pack[i] = v;                     // coalesced dwordx4 store
}

extern "C" __global__ void __launch_bounds__(64)
nerf_march_kernel(const float* __restrict__ ro,
                  const float* __restrict__ rd,
                  const float4* __restrict__ pack,
                  float* __restrict__ out, int R)
{
    const int r = blockIdx.x * 64 + threadIdx.x;
    if (r >= R) return;

    const float ox = ro[3 * r + 0];
    const float oy = ro[3 * r + 1];
    const float oz = ro[3 * r + 2];
    const float dx = rd[3 * r + 0];
    const float dy = rd[3 * r + 1];
    const float dz = rd[3 * r + 2];

    float c = 0.0f;                 // running (unclamped) cumsum of probs_raw
    float depth = 0.0f;
    float a0 = 0.0f, a1 = 0.0f, a2 = 0.0f;
    const float zlast = ZSTEP * (float)(NS - 1);   // 57.2

    #pragma unroll 1
    for (int n = 0; n < NS; ++n) {
        const float z  = ZSTEP * (float)n;
        const float px = fmaf(dx, z, ox);
        const float py = fmaf(dy, z, oy);
        const float pz = fmaf(dz, z, oz);

        const bool inside = (px >= -40.0f) & (px <= 40.0f) &
                            (py >= -40.0f) & (py <= 40.0f) &
                            (pz >= -1.0f)  & (pz <= 5.4f);
        if (!inside) {
            // prefix property: all remaining samples outside; only the forced
            // last sample (p_raw = 1) contributes, rgb zeroed outside.
            // loop invariant: c < 1 here (we break at saturation below).
            if (c < 1.0f) depth += (1.0f - c) * zlast;
            break;
        }

        // trilinear index/weights (align_corners=true: idx = u*(dim-1))
        // (px+40)/80*199 == px*2.4875 + 99.5 ; (pz+1)/6.4*15 == pz*2.34375 + 2.34375
        const float fx = fminf(fmaxf(fmaf(px, 2.4875f,  99.5f),    0.0f), 199.0f);
        const float fy = fminf(fmaxf(fmaf(py, 2.4875f,  99.5f),    0.0f), 199.0f);
        const float fz = fminf(fmaxf(fmaf(pz, 2.34375f, 2.34375f), 0.0f), 15.0f);
        const int ix = min((int)fx, DX - 2);   // fx >= 0 so cast == floor
        const int iy = min((int)fy, DY - 2);
        const int iz = min((int)fz, DZ - 2);
        const float wx = fx - (float)ix, wy = fy - (float)iy, wz = fz - (float)iz;
        const float ux = 1.0f - wx, uy = 1.0f - wy, uz = 1.0f - wz;

        const float w000 = ux * uy * uz, w001 = ux * uy * wz;
        const float w010 = ux * wy * uz, w011 = ux * wy * wz;
        const float w100 = wx * uy * uz, w101 = wx * uy * wz;
        const float w110 = wx * wy * uz, w111 = wx * wy * wz;

        const int base = (ix * DY + iy) * DZ + iz;
        constexpr int SX = DY * DZ;   // 3200 (float4 units)
        constexpr int SY = DZ;        // 16

        // 8 corner fetches, each one dwordx4 {dens, r, g, b}
        const float4 c000 = pack[base];
        const float4 c001 = pack[base + 1];
        const float4 c010 = pack[base + SY];
        const float4 c011 = pack[base + SY + 1];
        const float4 c100 = pack[base + SX];
        const float4 c101 = pack[base + SX + 1];
        const float4 c110 = pack[base + SX + SY];
        const float4 c111 = pack[base + SX + SY + 1];

        // accumulation order matches reference: 000..111
        const float dens =
            c000.x * w000 + c001.x * w001 + c010.x * w010 + c011.x * w011 +
            c100.x * w100 + c101.x * w101 + c110.x * w110 + c111.x * w111;

        const float sig = 1.0f / (1.0f + __expf(-dens));

        const float newc = c + sig;
        const float p = fminf(newc, 1.0f) - c;   // c < 1 invariant => min(c,1)==c

        depth += p * z;

        const float vr =
            c000.y * w000 + c001.y * w001 + c010.y * w010 + c011.y * w011 +
            c100.y * w100 + c101.y * w101 + c110.y * w110 + c111.y * w111;
        const float vg =
            c000.z * w000 + c001.z * w001 + c010.z * w010 + c011.z * w011 +
            c100.z * w100 + c101.z * w101 + c110.z * w110 + c111.z * w111;
        const float vb =
            c000.w * w000 + c001.w * w001 + c010.w * w010 + c011.w * w011 +
            c100.w * w100 + c101.w * w101 + c110.w * w110 + c111.w * w111;
        a0 += p * vr;
        a1 += p * vg;
        a2 += p * vb;

        c = newc;
        if (c >= 1.0f) break;   // saturated: every later probs[n] == 0
    }

    out[r]             = depth;
    out[R + 3 * r]     = a0;
    out[R + 3 * r + 1] = a1;
    out[R + 3 * r + 2] = a2;
}

extern "C" void kernel_launch(void* const* d_in, const int* in_sizes, int n_in,
                              void* d_out, int out_size, void* d_ws, size_t ws_size,
                              hipStream_t stream) {
    const float* ro   = (const float*)d_in[0];
    const float* rd   = (const float*)d_in[1];
    const float* vox  = (const float*)d_in[2];
    const float* rgbg = (const float*)d_in[3];
    float4* pack = (float4*)d_ws;          // 640000 * 16 B = 10.24 MB << ws
    float* out = (float*)d_out;

    const int R = in_sizes[0] / 3;         // 86400

    nerf_pack_kernel<<<(GRID_N + 255) / 256, 256, 0, stream>>>(vox, rgbg, pack);
    nerf_march_kernel<<<(R + 63) / 64, 64, 0, stream>>>(ro, rd, pack, out, R);
}